// Round 11
// baseline (275.689 us; speedup 1.0000x reference)
//
#include <hip/hip_runtime.h>
#include <hip/hip_bf16.h>

// B=2, H=16, L=2048, D=64. BH=32 flattened heads.
// MFMA flash attention, round 11 = round 10 with ADJACENT tile pairing.
//  Old pairing (qa, 31-qa): nkt = 64-2qa trips, light tile active only
//  2qa+2 of them -> light wave-group idle ~32 trips/block = ~33% of all
//  wave-trips (matches the 37.5/50 occupancy deficit; CU-mapping-independent).
//  New pairing (2p, 2p+1): nkt = 4p+4, light active 4p+2 -> idle = 2 trips.
//  Also cuts total staged sweeps/head from 784 to 544 tiles (-31% staging
//  VALU + FETCH): complementary pairing staged long sweeps the light tile
//  never consumed. Compute events unchanged (bijection over tiles kept).
// Carried: perm-packing, trip reorder (scores -> stage -> sm/PV), speculative
// exp, exp2-domain softmax, defer-max THR=8, setprio, swapped QK^T,
// in-register P (16 bpermute), K/E/V dbuf one-barrier/trip, staging role
// split, swizzled LDS, split-precision 3-MFMA scheme, rotation(+flip).
// Runtime dtype detection kept (flag in d_ws); both instantiations launch,
// wrong one early-exits. mask input (d_in[5]) is pure causal -> analytic.

typedef unsigned short u16;
typedef unsigned int   u32;
typedef __attribute__((ext_vector_type(8))) short bf16x8;  // 8 bf16 (4 VGPR)
typedef __attribute__((ext_vector_type(4))) float f32x4;   // MFMA acc

#define L_SEQ 2048
#define D_DIM 64
#define BQ    64            // q rows per tile = 4 waves x 16
#define BK    32            // keys per tile
#define NQT   (L_SEQ / BQ)  // 32 q-tiles per head

__device__ __forceinline__ float bf2f(u32 lo16) {
    u32 u = lo16 << 16; float f; __builtin_memcpy(&f, &u, 4); return f;
}

// [lo_src.hi16 | hi_src.hi16] in one v_perm_b32 (pool: idx0-3 = 2nd arg)
__device__ __forceinline__ u32 pack_hi16(u32 lo_src, u32 hi_src) {
    return __builtin_amdgcn_perm(hi_src, lo_src, 0x07060302u);
}

__global__ void detect_dtype_kernel(const u16* __restrict__ q, int* __restrict__ flag) {
    const int lane = threadIdx.x;             // 64 threads, 1 block
    float x = fabsf(bf2f((u32)q[lane]));
    bool big = !(x <= 100.f);                 // fp32 mantissa bits look like wild bf16
    unsigned long long m = __ballot(big);
    if (lane == 0) *flag = (m != 0ull) ? 1 : 0;  // 1 = fp32, 0 = bf16
}

// ---- truncating hi/lo split of 8 f32 -> packed bf16 uint4 pair ----
__device__ __forceinline__ void split_pack(const float* x, uint4& h, uint4& l) {
    u32 xb[8], rb[8];
#pragma unroll
    for (int j = 0; j < 8; ++j) {
        __builtin_memcpy(&xb[j], &x[j], 4);
        u32 hb = xb[j] & 0xffff0000u;
        float hf; __builtin_memcpy(&hf, &hb, 4);
        float r = x[j] - hf;                  // exact residual of truncation
        __builtin_memcpy(&rb[j], &r, 4);
    }
    h.x = pack_hi16(xb[0], xb[1]);
    h.y = pack_hi16(xb[2], xb[3]);
    h.z = pack_hi16(xb[4], xb[5]);
    h.w = pack_hi16(xb[6], xb[7]);
    l.x = pack_hi16(rb[0], rb[1]);
    l.y = pack_hi16(rb[2], rb[3]);
    l.z = pack_hi16(rb[4], rb[5]);
    l.w = pack_hi16(rb[6], rb[7]);
}

template<bool IS_F32>
__device__ __forceinline__ void unpack8(const uint4& a, const uint4& b, float* x) {
    if (IS_F32) {
        u32 w[8] = {a.x, a.y, a.z, a.w, b.x, b.y, b.z, b.w};
#pragma unroll
        for (int j = 0; j < 8; ++j) __builtin_memcpy(&x[j], &w[j], 4);
    } else {
        u32 w[4] = {a.x, a.y, a.z, a.w};
#pragma unroll
        for (int j = 0; j < 4; ++j) {
            x[2*j]   = bf2f(w[j] & 0xffffu);
            x[2*j+1] = bf2f(w[j] >> 16);
        }
    }
}

struct StKE { uint4 k0, k1, e0, e1; };   // bf16 path uses k0/e0 only
struct StV  { u32 v[8]; };

template<bool IS_F32>
__device__ __forceinline__ void issue_ke(const void* Kv, const void* Ev,
        size_t base, int kbase, int r, int j8, StKE& R) {
    const size_t off = base + (size_t)(kbase + r) * D_DIM + j8 * 8;
    if (IS_F32) {
        const uint4* kp = (const uint4*)((const float*)Kv + off);
        R.k0 = kp[0]; R.k1 = kp[1];
        const uint4* ep = (const uint4*)((const float*)Ev + off);
        R.e0 = ep[0]; R.e1 = ep[1];
    } else {
        R.k0 = *(const uint4*)((const u16*)Kv + off);
        R.e0 = *(const uint4*)((const u16*)Ev + off);
    }
}

template<bool IS_F32>
__device__ __forceinline__ void issue_v(const void* Vv,
        size_t base, int kbase, int d, int kg, StV& R) {
    const size_t off = base + (size_t)(kbase + kg * 8) * D_DIM + d;
    if (IS_F32) {
        const u32* vp = (const u32*)((const float*)Vv + off);
#pragma unroll
        for (int j = 0; j < 8; ++j) R.v[j] = vp[j * D_DIM];   // one dim, 8 keys
    } else {
        const u16* vp = (const u16*)Vv + off;
#pragma unroll
        for (int j = 0; j < 8; ++j) R.v[j] = (u32)vp[j * D_DIM];
    }
}

#define MFMA(a, b, c) __builtin_amdgcn_mfma_f32_16x16x32_bf16((a), (b), (c), 0, 0, 0)

template<bool IS_F32>
__global__ __launch_bounds__(512, 4) void attn_pair(
    const void* __restrict__ Qv, const void* __restrict__ Kv,
    const void* __restrict__ Vv, const void* __restrict__ PQv,
    const void* __restrict__ PKv, void* __restrict__ Ov,
    const int* __restrict__ flag)
{
    if (((*flag) != 0) != IS_F32) return;    // wrong dtype for this instantiation

    const int bh   = blockIdx.y;
    int p = ((int)blockIdx.x + bh) & 15;     // rotation mixes lengths
    if (bh & 16) p = 15 - p;                 // (kept from r10; free)
    const int t    = threadIdx.x;
    const int w    = t >> 6;                 // wave 0..7
    const int lane = t & 63;
    const int g    = lane >> 4;              // 16-lane group 0..3
    const int c    = lane & 15;
    const size_t base = (size_t)bh * L_SEQ * D_DIM;
    const int qtile = (w < 4) ? (2 * p) : (2 * p + 1);  // adjacent pair
    const int qb_w  = qtile * BQ + (w & 3) * 16;        // wave's first q row
    const int nkt   = 4 * p + 4;             // heavy tile's k-tile count

    // LDS: double-buffered swizzled tile images (rows 256B, 16B slots XOR'd).
    __shared__ __align__(16) u16 Kt[2][BK * 128];     // 16 KB
    __shared__ __align__(16) u16 Et[2][BK * 128];     // 16 KB
    __shared__ __align__(16) u16 Vt[2][32 * 128];     // 16 KB
    // total 48 KB -> 2 blocks/CU (grid is 2/CU anyway)

    // ---- Q & PE_Q fragments, pre-scaled by 0.125*log2(e) (exp2 domain) ----
    bf16x8 qa_h[4], qa_l[4];                 // ch 0,1 = Q d0=0,32 ; ch 2,3 = PE_Q
    {
        const int qrow = qb_w + c;
#pragma unroll
        for (int ch = 0; ch < 4; ++ch) {
            const void* src = (ch < 2) ? Qv : PQv;
            const int d0 = (ch & 1) * 32 + 8 * g;
            const size_t off = base + (size_t)qrow * D_DIM + d0;
            float x[8];
            if (IS_F32) {
                const uint4* gp = (const uint4*)((const float*)src + off);
                unpack8<true>(gp[0], gp[1], x);
            } else {
                uint4 a = *(const uint4*)((const u16*)src + off);
                unpack8<false>(a, a, x);
            }
#pragma unroll
            for (int j = 0; j < 8; ++j) x[j] *= 0.1803368801f;  // (1/8)*log2(e)
            uint4 hp, lp; split_pack(x, hp, lp);
            u32 hw[4] = {hp.x, hp.y, hp.z, hp.w}, lw[4] = {lp.x, lp.y, lp.z, lp.w};
#pragma unroll
            for (int j = 0; j < 4; ++j) {
                qa_h[ch][2*j]   = (short)(hw[j] & 0xffffu);
                qa_h[ch][2*j+1] = (short)(hw[j] >> 16);
                qa_l[ch][2*j]   = (short)(lw[j] & 0xffffu);
                qa_l[ch][2*j+1] = (short)(lw[j] >> 16);
            }
        }
    }

    float mr = -INFINITY, lr = 0.f;          // scalar stats (log2-domain max)
    f32x4 acc[4];
#pragma unroll
    for (int df = 0; df < 4; ++df) acc[df] = (f32x4){0.f, 0.f, 0.f, 0.f};

    // ---- staging roles: waves 0-3 stage K+PE, waves 4-7 stage V ----
    const bool is_ke = (t < 256);
    const int ts   = t & 255;
    const int r_t  = ts >> 3;                // K/E: row (key) 0..31
    const int j8_t = ts & 7;                 // K/E: 8-elem chunk 0..7
    const int d_t  = ts & 63;                // V: dim 0..63
    const int kg_t = (ts >> 6) & 3;          // V: key chunk 0..3
    const int ke_wo = r_t * 128 + (j8_t ^ (r_t & 7)) * 8;           // hi; lo at +64
    const int v_rr  = d_t >> 1;
    const int v_wo  = v_rr * 128 + ((4 * (d_t & 1) + kg_t) ^ (v_rr & 7)) * 8;

    StKE Rke; StV Rv;

    auto stage_store = [&](int b) {
        if (is_ke) {
            float x[8]; uint4 hp, lp;
            unpack8<IS_F32>(Rke.k0, Rke.k1, x);
            split_pack(x, hp, lp);
            *(uint4*)(&Kt[b][0] + ke_wo)      = hp;
            *(uint4*)(&Kt[b][0] + ke_wo + 64) = lp;
            unpack8<IS_F32>(Rke.e0, Rke.e1, x);
            split_pack(x, hp, lp);
            *(uint4*)(&Et[b][0] + ke_wo)      = hp;
            *(uint4*)(&Et[b][0] + ke_wo + 64) = lp;
        } else {
            float x[8]; uint4 hp, lp;
#pragma unroll
            for (int j = 0; j < 8; ++j) {
                if (IS_F32) __builtin_memcpy(&x[j], &Rv.v[j], 4);
                else        x[j] = bf2f(Rv.v[j]);
            }
            split_pack(x, hp, lp);
            *(uint4*)(&Vt[b][0] + v_wo)      = hp;
            *(uint4*)(&Vt[b][0] + v_wo + 64) = lp;
        }
    };
    auto issue = [&](int kbase) {
        if (is_ke) issue_ke<IS_F32>(Kv, PKv, base, kbase, r_t, j8_t, Rke);
        else       issue_v <IS_F32>(Vv, base, kbase, d_t, kg_t, Rv);
    };

    // ---- prologue: tile 0 into buf 0; tile 1 in flight (nkt >= 4) ----
    issue(0);
    stage_store(0);
    issue(BK);
    __syncthreads();

    const int c7 = c & 7;
    const int srcA = 32 * (g & 1) + c;       // P-shuffle sources (own column)
    const int srcB = srcA + 16;
    const int sv = ((4 * (c & 1) + g) ^ ((c >> 1) & 7)) * 8;  // V/P slot formula

    for (int kt = 0; kt < nkt; ++kt) {
        const int cur = kt & 1;
        const int kbase = kt * BK;
        const bool active = (kbase <= qb_w + 15);   // wave-uniform
        const bool do1 = (kbase + 16 <= qb_w + 15);

        // ---- (1) scores first: S^T = K.Q^T (+ PEk.PEq^T), split precision ----
        // Lane (g,c): s0[i] = S[key kbase+4g+i][query qb_w+c], s1: key+16.
        f32x4 s0 = {0,0,0,0}, s1 = {0,0,0,0};
        if (active) {
            const u16* Ktc = &Kt[cur][0];
            const u16* Etc = &Et[cur][0];
            __builtin_amdgcn_s_setprio(1);
#pragma unroll
            for (int ch = 0; ch < 4; ++ch) {
                const u16* Bp = (ch < 2) ? Ktc : Etc;
                const int sh = ((((ch & 1) * 4 + g) ^ c7)) * 8;
                const u16* r0 = Bp + c * 128;
                bf16x8 b0h = *(const bf16x8*)(r0 + sh);
                bf16x8 b0l = *(const bf16x8*)(r0 + sh + 64);
                s0 = MFMA(b0h, qa_h[ch], s0);    // Kh.Qh
                s0 = MFMA(b0l, qa_h[ch], s0);    // Kl.Qh
                s0 = MFMA(b0h, qa_l[ch], s0);    // Kh.Ql
                if (do1) {
                    const u16* r1 = Bp + (c + 16) * 128;   // (c+16)&7 == c&7
                    bf16x8 b1h = *(const bf16x8*)(r1 + sh);
                    bf16x8 b1l = *(const bf16x8*)(r1 + sh + 64);
                    s1 = MFMA(b1h, qa_h[ch], s1);
                    s1 = MFMA(b1l, qa_h[ch], s1);
                    s1 = MFMA(b1h, qa_l[ch], s1);
                }
            }
            __builtin_amdgcn_s_setprio(0);
        }

        // ---- (2) stage next tile (VALU overlaps score-MFMA latency drain) ----
        if (kt + 1 < nkt) {
            stage_store(cur ^ 1);
            if (kt + 2 < nkt) issue(kbase + 2 * BK);
        }

        // ---- (3) softmax + P + PV ----
        if (active) {
            const u16* Vtc = &Vt[cur][0];
            // causal mask (rows = keys now): key > query -> -inf
            const int qrow = qb_w + c;
#pragma unroll
            for (int i = 0; i < 4; ++i) {
                if (kbase + 4 * g + i > qrow)                s0[i] = -INFINITY;
                if (!do1 || kbase + 16 + 4 * g + i > qrow)   s1[i] = -INFINITY;
            }
            // vm reduce (DS pipe) runs concurrently with speculative exps (trans)
            float vm = fmaxf(fmaxf(fmaxf(s0[0], s0[1]), fmaxf(s0[2], s0[3])),
                             fmaxf(fmaxf(s1[0], s1[1]), fmaxf(s1[2], s1[3])));
            vm = fmaxf(vm, __shfl_xor(vm, 16));
            vm = fmaxf(vm, __shfl_xor(vm, 32));
            float p0f[4], p1f[4];
#pragma unroll
            for (int i = 0; i < 4; ++i) {        // speculative: old mr
                p0f[i] = exp2f(s0[i] - mr);
                p1f[i] = exp2f(s1[i] - mr);
            }
            if (!__all(vm <= mr + 8.f)) {        // rescale (always on trip 0)
                const float mn = fmaxf(mr, vm);
                const float al = exp2f(mr - mn); // exp2(-inf)=0 on first tile
                mr = mn;
                lr *= al;
                float al4[4];
#pragma unroll
                for (int i = 0; i < 4; ++i) al4[i] = __shfl(al, 20 * g + i);
#pragma unroll
                for (int df = 0; df < 4; ++df) {
#pragma unroll
                    for (int i = 0; i < 4; ++i) acc[df][i] *= al4[i];
                }
#pragma unroll
                for (int i = 0; i < 4; ++i) {    // full recompute (spec discarded)
                    p0f[i] = exp2f(s0[i] - mr);
                    p1f[i] = exp2f(s1[i] - mr);
                }
            }
            float rs = (p0f[0] + p0f[1]) + (p0f[2] + p0f[3])
                     + (p1f[0] + p1f[1]) + (p1f[2] + p1f[3]);
            rs += __shfl_xor(rs, 16);
            rs += __shfl_xor(rs, 32);
            lr += rs;
            // ---- P -> PV A-fragment, fully in-register (perm-packed) ----
            u32 w0[4], w1[4];
#pragma unroll
            for (int i = 0; i < 4; ++i) {
                const float x0 = p0f[i];
                u32 b0; __builtin_memcpy(&b0, &x0, 4);
                u32 h0 = b0 & 0xffff0000u; float h0f; __builtin_memcpy(&h0f, &h0, 4);
                float l0f = x0 - h0f; u32 l0; __builtin_memcpy(&l0, &l0f, 4);
                w0[i] = pack_hi16(b0, l0);       // [p_hi | residual_hi]
                const float x1 = p1f[i];
                u32 b1; __builtin_memcpy(&b1, &x1, 4);
                u32 h1 = b1 & 0xffff0000u; float h1f; __builtin_memcpy(&h1f, &h1, 4);
                float l1f = x1 - h1f; u32 l1; __builtin_memcpy(&l1, &l1f, 4);
                w1[i] = pack_hi16(b1, l1);
            }
            const bool lowhalf = (lane < 32);    // g<2 -> keys<16 -> p0 array
            bf16x8 pa_h, pa_l;
#pragma unroll
            for (int i = 0; i < 4; ++i) {
                u32 t0a = (u32)__shfl((int)w0[i], srcA);
                u32 t1a = (u32)__shfl((int)w1[i], srcA);
                u32 t0b = (u32)__shfl((int)w0[i], srcB);
                u32 t1b = (u32)__shfl((int)w1[i], srcB);
                u32 ha = lowhalf ? t0a : t1a;
                u32 hb = lowhalf ? t0b : t1b;
                pa_h[i]     = (short)(ha & 0xffffu);
                pa_h[4 + i] = (short)(hb & 0xffffu);
                pa_l[i]     = (short)(ha >> 16);
                pa_l[4 + i] = (short)(hb >> 16);
            }
            // ---- PV: acc += P.V (split precision: PhVh + PhVl + PlVh) ----
            __builtin_amdgcn_s_setprio(1);
#pragma unroll
            for (int df = 0; df < 4; ++df) {
                const u16* vw = Vtc + (8 * df + (c >> 1)) * 128;
                bf16x8 vbh = *(const bf16x8*)(vw + sv);
                bf16x8 vbl = *(const bf16x8*)(vw + sv + 64);
                acc[df] = MFMA(pa_h, vbh, acc[df]);
                acc[df] = MFMA(pa_h, vbl, acc[df]);
                acc[df] = MFMA(pa_l, vbh, acc[df]);
            }
            __builtin_amdgcn_s_setprio(0);
        }
        __syncthreads();                     // end of trip: buf^1 now complete
    }

    // ---- epilogue: 1/l for query 4g+i lives at lane 20g+i ----
    float inv[4];
#pragma unroll
    for (int i = 0; i < 4; ++i) inv[i] = 1.f / __shfl(lr, 20 * g + i);
    if (IS_F32) {
        float* o = (float*)Ov + base;
#pragma unroll
        for (int df = 0; df < 4; ++df)
#pragma unroll
            for (int i = 0; i < 4; ++i)
                o[(size_t)(qb_w + 4 * g + i) * D_DIM + 16 * df + c] = acc[df][i] * inv[i];
    } else {
        __hip_bfloat16* o = (__hip_bfloat16*)Ov + base;
#pragma unroll
        for (int df = 0; df < 4; ++df)
#pragma unroll
            for (int i = 0; i < 4; ++i)
                o[(size_t)(qb_w + 4 * g + i) * D_DIM + 16 * df + c] =
                    __float2bfloat16(acc[df][i] * inv[i]);
    }
}

extern "C" void kernel_launch(void* const* d_in, const int* in_sizes, int n_in,
                              void* d_out, int out_size, void* d_ws, size_t ws_size,
                              hipStream_t stream) {
    const void* q  = d_in[0];
    const void* k  = d_in[1];
    const void* v  = d_in[2];
    const void* pq = d_in[3];
    const void* pk = d_in[4];
    // d_in[5] = causal mask, recomputed analytically in-kernel.
    int* flag = (int*)d_ws;

    detect_dtype_kernel<<<1, 64, 0, stream>>>((const u16*)q, flag);

    dim3 grid(NQT / 2, 32);                  // 16 pairs x 32 heads = 512 blocks
    attn_pair<false><<<grid, 512, 0, stream>>>(q, k, v, pq, pk, d_out, flag);
    attn_pair<true ><<<grid, 512, 0, stream>>>(q, k, v, pq, pk, d_out, flag);
}

// Round 12
// 269.242 us; speedup vs baseline: 1.0239x; 1.0239x over previous
//
#include <hip/hip_runtime.h>
#include <hip/hip_bf16.h>

// B=2, H=16, L=2048, D=64. BH=32 flattened heads.
// MFMA flash attention, round 12: UNIFORM 34-trip blocks via split-K halves.
//  r10 (null) + r11 (regression) proved block->CU mapping is unsteerable;
//  the only mapping-proof schedule is identical-length blocks.
//  Block (q=0..7, h=0..1): sweep half h of super-tile q (2q+2 k-tiles), dump
//  flash partials (O,m,l) to ws; then half h of super-tile 15-q (32-2q).
//  Total = 34 trips for EVERY block -> any 2-per-CU mapping gives 68/CU.
//  merge_kernel combines the two halves per row (flash merge; h=0 always
//  has key 0 -> m0 finite, l0>0; dead partials weight to 0 naturally).
//  Workspace 34.6MB (proven >=50.3MB available in round 4); else fallback
//  to the proven round-10 kernel.
// Inner trip code byte-identical to r9/r10 (157us proven): perm-packing,
// scores->stage->softmax/PV order, speculative exp, exp2 softmax, defer-max,
// setprio, swapped QK^T, in-register P, K/E/V dbuf, role split, swizzled LDS,
// split-precision 3-MFMA. mask input (d_in[5]) = pure causal -> analytic.

typedef unsigned short u16;
typedef unsigned int   u32;
typedef __attribute__((ext_vector_type(8))) short bf16x8;  // 8 bf16 (4 VGPR)
typedef __attribute__((ext_vector_type(4))) float f32x4;   // MFMA acc

#define L_SEQ 2048
#define D_DIM 64
#define BQ    64
#define BK    32
#define NQT   (L_SEQ / BQ)

__device__ __forceinline__ float bf2f(u32 lo16) {
    u32 u = lo16 << 16; float f; __builtin_memcpy(&f, &u, 4); return f;
}

__device__ __forceinline__ u32 pack_hi16(u32 lo_src, u32 hi_src) {
    return __builtin_amdgcn_perm(hi_src, lo_src, 0x07060302u);
}

__global__ void detect_dtype_kernel(const u16* __restrict__ q, int* __restrict__ flag) {
    const int lane = threadIdx.x;
    float x = fabsf(bf2f((u32)q[lane]));
    bool big = !(x <= 100.f);
    unsigned long long m = __ballot(big);
    if (lane == 0) *flag = (m != 0ull) ? 1 : 0;  // 1 = fp32, 0 = bf16
}

__device__ __forceinline__ void split_pack(const float* x, uint4& h, uint4& l) {
    u32 xb[8], rb[8];
#pragma unroll
    for (int j = 0; j < 8; ++j) {
        __builtin_memcpy(&xb[j], &x[j], 4);
        u32 hb = xb[j] & 0xffff0000u;
        float hf; __builtin_memcpy(&hf, &hb, 4);
        float r = x[j] - hf;
        __builtin_memcpy(&rb[j], &r, 4);
    }
    h.x = pack_hi16(xb[0], xb[1]);
    h.y = pack_hi16(xb[2], xb[3]);
    h.z = pack_hi16(xb[4], xb[5]);
    h.w = pack_hi16(xb[6], xb[7]);
    l.x = pack_hi16(rb[0], rb[1]);
    l.y = pack_hi16(rb[2], rb[3]);
    l.z = pack_hi16(rb[4], rb[5]);
    l.w = pack_hi16(rb[6], rb[7]);
}

template<bool IS_F32>
__device__ __forceinline__ void unpack8(const uint4& a, const uint4& b, float* x) {
    if (IS_F32) {
        u32 w[8] = {a.x, a.y, a.z, a.w, b.x, b.y, b.z, b.w};
#pragma unroll
        for (int j = 0; j < 8; ++j) __builtin_memcpy(&x[j], &w[j], 4);
    } else {
        u32 w[4] = {a.x, a.y, a.z, a.w};
#pragma unroll
        for (int j = 0; j < 4; ++j) {
            x[2*j]   = bf2f(w[j] & 0xffffu);
            x[2*j+1] = bf2f(w[j] >> 16);
        }
    }
}

struct StKE { uint4 k0, k1, e0, e1; };
struct StV  { u32 v[8]; };

template<bool IS_F32>
__device__ __forceinline__ void issue_ke(const void* Kv, const void* Ev,
        size_t base, int kbase, int r, int j8, StKE& R) {
    const size_t off = base + (size_t)(kbase + r) * D_DIM + j8 * 8;
    if (IS_F32) {
        const uint4* kp = (const uint4*)((const float*)Kv + off);
        R.k0 = kp[0]; R.k1 = kp[1];
        const uint4* ep = (const uint4*)((const float*)Ev + off);
        R.e0 = ep[0]; R.e1 = ep[1];
    } else {
        R.k0 = *(const uint4*)((const u16*)Kv + off);
        R.e0 = *(const uint4*)((const u16*)Ev + off);
    }
}

template<bool IS_F32>
__device__ __forceinline__ void issue_v(const void* Vv,
        size_t base, int kbase, int d, int kg, StV& R) {
    const size_t off = base + (size_t)(kbase + kg * 8) * D_DIM + d;
    if (IS_F32) {
        const u32* vp = (const u32*)((const float*)Vv + off);
#pragma unroll
        for (int j = 0; j < 8; ++j) R.v[j] = vp[j * D_DIM];
    } else {
        const u16* vp = (const u16*)Vv + off;
#pragma unroll
        for (int j = 0; j < 8; ++j) R.v[j] = (u32)vp[j * D_DIM];
    }
}

#define MFMA(a, b, c) __builtin_amdgcn_mfma_f32_16x16x32_bf16((a), (b), (c), 0, 0, 0)

// ==================== pass 1: uniform 34-trip split blocks ====================
template<bool IS_F32>
__global__ __launch_bounds__(512, 4) void attn_split(
    const void* __restrict__ Qv, const void* __restrict__ Kv,
    const void* __restrict__ Vv, const void* __restrict__ PQv,
    const void* __restrict__ PKv, float* __restrict__ O_ws,
    float* __restrict__ ml_ws, const int* __restrict__ flag)
{
    if (((*flag) != 0) != IS_F32) return;

    const int bh = blockIdx.y;
    const int q  = (int)blockIdx.x >> 1;     // super-pair 0..7
    const int h  = (int)blockIdx.x & 1;      // k-half 0..1
    const int t    = threadIdx.x;
    const int w    = t >> 6;
    const int lane = t & 63;
    const int g    = lane >> 4;
    const int c    = lane & 15;
    const size_t base = (size_t)bh * L_SEQ * D_DIM;

    __shared__ __align__(16) u16 Kt[2][BK * 128];     // 16 KB
    __shared__ __align__(16) u16 Et[2][BK * 128];     // 16 KB
    __shared__ __align__(16) u16 Vt[2][32 * 128];     // 16 KB

    // staging roles: waves 0-3 stage K+PE, waves 4-7 stage V
    const bool is_ke = (t < 256);
    const int ts   = t & 255;
    const int r_t  = ts >> 3;
    const int j8_t = ts & 7;
    const int d_t  = ts & 63;
    const int kg_t = (ts >> 6) & 3;
    const int ke_wo = r_t * 128 + (j8_t ^ (r_t & 7)) * 8;
    const int v_rr  = d_t >> 1;
    const int v_wo  = v_rr * 128 + ((4 * (d_t & 1) + kg_t) ^ (v_rr & 7)) * 8;

    StKE Rke; StV Rv;

    auto stage_store = [&](int b) {
        if (is_ke) {
            float x[8]; uint4 hp, lp;
            unpack8<IS_F32>(Rke.k0, Rke.k1, x);
            split_pack(x, hp, lp);
            *(uint4*)(&Kt[b][0] + ke_wo)      = hp;
            *(uint4*)(&Kt[b][0] + ke_wo + 64) = lp;
            unpack8<IS_F32>(Rke.e0, Rke.e1, x);
            split_pack(x, hp, lp);
            *(uint4*)(&Et[b][0] + ke_wo)      = hp;
            *(uint4*)(&Et[b][0] + ke_wo + 64) = lp;
        } else {
            float x[8]; uint4 hp, lp;
#pragma unroll
            for (int j = 0; j < 8; ++j) {
                if (IS_F32) __builtin_memcpy(&x[j], &Rv.v[j], 4);
                else        x[j] = bf2f(Rv.v[j]);
            }
            split_pack(x, hp, lp);
            *(uint4*)(&Vt[b][0] + v_wo)      = hp;
            *(uint4*)(&Vt[b][0] + v_wo + 64) = lp;
        }
    };
    auto issue = [&](int kb) {
        if (is_ke) issue_ke<IS_F32>(Kv, PKv, base, kb, r_t, j8_t, Rke);
        else       issue_v <IS_F32>(Vv, base, kb, d_t, kg_t, Rv);
    };

    const int c7 = c & 7;
    const int srcA = 32 * (g & 1) + c;
    const int srcB = srcA + 16;
    const int sv = ((4 * (c & 1) + g) ^ ((c >> 1) & 7)) * 8;

    for (int seg = 0; seg < 2; ++seg) {
        const int s    = seg ? (15 - q) : q;     // super-tile 0..15
        const int half = 2 * s + 2;              // k-tiles per half
        const int k0   = h ? half : 0;
        const int klim = k0 + half;
        const int qtile = 2 * s + ((w >= 4) ? 1 : 0);
        const int qb_w  = qtile * BQ + (w & 3) * 16;

        // ---- Q & PE_Q fragments, pre-scaled by 0.125*log2(e) ----
        bf16x8 qa_h[4], qa_l[4];
        {
            const int qrow = qb_w + c;
#pragma unroll
            for (int ch = 0; ch < 4; ++ch) {
                const void* src = (ch < 2) ? Qv : PQv;
                const int d0 = (ch & 1) * 32 + 8 * g;
                const size_t off = base + (size_t)qrow * D_DIM + d0;
                float x[8];
                if (IS_F32) {
                    const uint4* gp = (const uint4*)((const float*)src + off);
                    unpack8<true>(gp[0], gp[1], x);
                } else {
                    uint4 a = *(const uint4*)((const u16*)src + off);
                    unpack8<false>(a, a, x);
                }
#pragma unroll
                for (int j = 0; j < 8; ++j) x[j] *= 0.1803368801f;
                uint4 hp, lp; split_pack(x, hp, lp);
                u32 hw[4] = {hp.x, hp.y, hp.z, hp.w}, lw[4] = {lp.x, lp.y, lp.z, lp.w};
#pragma unroll
                for (int j = 0; j < 4; ++j) {
                    qa_h[ch][2*j]   = (short)(hw[j] & 0xffffu);
                    qa_h[ch][2*j+1] = (short)(hw[j] >> 16);
                    qa_l[ch][2*j]   = (short)(lw[j] & 0xffffu);
                    qa_l[ch][2*j+1] = (short)(lw[j] >> 16);
                }
            }
        }

        float mr = -INFINITY, lr = 0.f;
        f32x4 acc[4];
#pragma unroll
        for (int df = 0; df < 4; ++df) acc[df] = (f32x4){0.f, 0.f, 0.f, 0.f};

        // prologue (half >= 2 always)
        issue(k0 * BK);
        stage_store(0);
        issue((k0 + 1) * BK);
        __syncthreads();

        for (int kt = k0; kt < klim; ++kt) {
            const int cur = (kt - k0) & 1;
            const int kbase = kt * BK;
            const bool active = (kbase <= qb_w + 15);
            const bool do1 = (kbase + 16 <= qb_w + 15);

            // ---- (1) scores: S^T = K.Q^T (+ PEk.PEq^T), split precision ----
            f32x4 s0 = {0,0,0,0}, s1 = {0,0,0,0};
            if (active) {
                const u16* Ktc = &Kt[cur][0];
                const u16* Etc = &Et[cur][0];
                __builtin_amdgcn_s_setprio(1);
#pragma unroll
                for (int ch = 0; ch < 4; ++ch) {
                    const u16* Bp = (ch < 2) ? Ktc : Etc;
                    const int sh = ((((ch & 1) * 4 + g) ^ c7)) * 8;
                    const u16* r0 = Bp + c * 128;
                    bf16x8 b0h = *(const bf16x8*)(r0 + sh);
                    bf16x8 b0l = *(const bf16x8*)(r0 + sh + 64);
                    s0 = MFMA(b0h, qa_h[ch], s0);
                    s0 = MFMA(b0l, qa_h[ch], s0);
                    s0 = MFMA(b0h, qa_l[ch], s0);
                    if (do1) {
                        const u16* r1 = Bp + (c + 16) * 128;
                        bf16x8 b1h = *(const bf16x8*)(r1 + sh);
                        bf16x8 b1l = *(const bf16x8*)(r1 + sh + 64);
                        s1 = MFMA(b1h, qa_h[ch], s1);
                        s1 = MFMA(b1l, qa_h[ch], s1);
                        s1 = MFMA(b1h, qa_l[ch], s1);
                    }
                }
                __builtin_amdgcn_s_setprio(0);
            }

            // ---- (2) stage next tile ----
            if (kt + 1 < klim) {
                stage_store(cur ^ 1);
                if (kt + 2 < klim) issue((kt + 2) * BK);
            }

            // ---- (3) softmax + P + PV ----
            if (active) {
                const u16* Vtc = &Vt[cur][0];
                const int qrow = qb_w + c;
#pragma unroll
                for (int i = 0; i < 4; ++i) {
                    if (kbase + 4 * g + i > qrow)                s0[i] = -INFINITY;
                    if (!do1 || kbase + 16 + 4 * g + i > qrow)   s1[i] = -INFINITY;
                }
                float vm = fmaxf(fmaxf(fmaxf(s0[0], s0[1]), fmaxf(s0[2], s0[3])),
                                 fmaxf(fmaxf(s1[0], s1[1]), fmaxf(s1[2], s1[3])));
                vm = fmaxf(vm, __shfl_xor(vm, 16));
                vm = fmaxf(vm, __shfl_xor(vm, 32));
                float p0f[4], p1f[4];
#pragma unroll
                for (int i = 0; i < 4; ++i) {
                    p0f[i] = exp2f(s0[i] - mr);
                    p1f[i] = exp2f(s1[i] - mr);
                }
                if (!__all(vm <= mr + 8.f)) {
                    // clamp kills the -inf-(-inf) NaN class for dead lanes
                    const float mn = fmaxf(fmaxf(mr, vm), -1.0e30f);
                    const float al = exp2f(mr - mn);
                    mr = mn;
                    lr *= al;
                    float al4[4];
#pragma unroll
                    for (int i = 0; i < 4; ++i) al4[i] = __shfl(al, 20 * g + i);
#pragma unroll
                    for (int df = 0; df < 4; ++df) {
#pragma unroll
                        for (int i = 0; i < 4; ++i) acc[df][i] *= al4[i];
                    }
#pragma unroll
                    for (int i = 0; i < 4; ++i) {
                        p0f[i] = exp2f(s0[i] - mr);
                        p1f[i] = exp2f(s1[i] - mr);
                    }
                }
                float rs = (p0f[0] + p0f[1]) + (p0f[2] + p0f[3])
                         + (p1f[0] + p1f[1]) + (p1f[2] + p1f[3]);
                rs += __shfl_xor(rs, 16);
                rs += __shfl_xor(rs, 32);
                lr += rs;
                u32 w0[4], w1[4];
#pragma unroll
                for (int i = 0; i < 4; ++i) {
                    const float x0 = p0f[i];
                    u32 b0; __builtin_memcpy(&b0, &x0, 4);
                    u32 h0 = b0 & 0xffff0000u; float h0f; __builtin_memcpy(&h0f, &h0, 4);
                    float l0f = x0 - h0f; u32 l0; __builtin_memcpy(&l0, &l0f, 4);
                    w0[i] = pack_hi16(b0, l0);
                    const float x1 = p1f[i];
                    u32 b1; __builtin_memcpy(&b1, &x1, 4);
                    u32 h1 = b1 & 0xffff0000u; float h1f; __builtin_memcpy(&h1f, &h1, 4);
                    float l1f = x1 - h1f; u32 l1; __builtin_memcpy(&l1, &l1f, 4);
                    w1[i] = pack_hi16(b1, l1);
                }
                const bool lowhalf = (lane < 32);
                bf16x8 pa_h, pa_l;
#pragma unroll
                for (int i = 0; i < 4; ++i) {
                    u32 t0a = (u32)__shfl((int)w0[i], srcA);
                    u32 t1a = (u32)__shfl((int)w1[i], srcA);
                    u32 t0b = (u32)__shfl((int)w0[i], srcB);
                    u32 t1b = (u32)__shfl((int)w1[i], srcB);
                    u32 ha = lowhalf ? t0a : t1a;
                    u32 hb = lowhalf ? t0b : t1b;
                    pa_h[i]     = (short)(ha & 0xffffu);
                    pa_h[4 + i] = (short)(hb & 0xffffu);
                    pa_l[i]     = (short)(ha >> 16);
                    pa_l[4 + i] = (short)(hb >> 16);
                }
                __builtin_amdgcn_s_setprio(1);
#pragma unroll
                for (int df = 0; df < 4; ++df) {
                    const u16* vw = Vtc + (8 * df + (c >> 1)) * 128;
                    bf16x8 vbh = *(const bf16x8*)(vw + sv);
                    bf16x8 vbl = *(const bf16x8*)(vw + sv + 64);
                    acc[df] = MFMA(pa_h, vbh, acc[df]);
                    acc[df] = MFMA(pa_h, vbl, acc[df]);
                    acc[df] = MFMA(pa_l, vbh, acc[df]);
                }
                __builtin_amdgcn_s_setprio(0);
            }
            __syncthreads();
        }

        // ---- dump partials for this segment (no LDS; safe vs next prologue) ----
        const size_t pb = (size_t)h * 32 + bh;
        float* Op  = O_ws  + pb * (size_t)L_SEQ * D_DIM;
        float* mlp = ml_ws + pb * (size_t)L_SEQ * 2;
#pragma unroll
        for (int df = 0; df < 4; ++df)
#pragma unroll
            for (int i = 0; i < 4; ++i)
                Op[(size_t)(qb_w + 4 * g + i) * D_DIM + 16 * df + c] = acc[df][i];
        float mrow = __shfl(mr, 20 * g + (c & 3));
        float lrow = __shfl(lr, 20 * g + (c & 3));
        if (c < 4) {
            mlp[(size_t)(qb_w + 4 * g + c) * 2]     = mrow;
            mlp[(size_t)(qb_w + 4 * g + c) * 2 + 1] = lrow;
        }
    }
}

// ==================== pass 2: flash merge of the two halves ====================
template<bool IS_F32>
__global__ __launch_bounds__(64) void merge_kernel(
    const float* __restrict__ O_ws, const float* __restrict__ ml_ws,
    void* __restrict__ Ov, const int* __restrict__ flag)
{
    if (((*flag) != 0) != IS_F32) return;
    const int row = blockIdx.x;              // 0..2047
    const int bh  = blockIdx.y;              // 0..31
    const int d   = threadIdx.x;             // 0..63
    const size_t idx = (size_t)bh * L_SEQ + row;
    const size_t hstride_ml = (size_t)32 * L_SEQ * 2;
    const size_t hstride_o  = (size_t)32 * L_SEQ * D_DIM;
    const float m0 = ml_ws[idx * 2],              l0 = ml_ws[idx * 2 + 1];
    const float m1 = ml_ws[hstride_ml + idx * 2], l1 = ml_ws[hstride_ml + idx * 2 + 1];
    const float m  = fmaxf(m0, m1);          // m0 finite, l0>0 (h=0 has key 0)
    const float w0 = exp2f(m0 - m);
    const float w1 = exp2f(m1 - m);          // m1=-inf -> 0
    const float l  = l0 * w0 + l1 * w1;
    const float o  = (O_ws[idx * D_DIM + d] * w0
                    + O_ws[hstride_o + idx * D_DIM + d] * w1) / l;
    if (IS_F32) ((float*)Ov)[idx * D_DIM + d] = o;
    else ((__hip_bfloat16*)Ov)[idx * D_DIM + d] = __float2bfloat16(o);
}

// ==================== fallback: round-10 kernel (proven 157us) ====================
template<bool IS_F32>
__global__ __launch_bounds__(512, 4) void attn_fb(
    const void* __restrict__ Qv, const void* __restrict__ Kv,
    const void* __restrict__ Vv, const void* __restrict__ PQv,
    const void* __restrict__ PKv, void* __restrict__ Ov,
    const int* __restrict__ flag)
{
    if (((*flag) != 0) != IS_F32) return;
    const int bh = blockIdx.y;
    int qa = ((int)blockIdx.x + bh) & 15;
    if (bh & 16) qa = 15 - qa;
    const int t = threadIdx.x, w = t >> 6, lane = t & 63, g = lane >> 4, c = lane & 15;
    const size_t base = (size_t)bh * L_SEQ * D_DIM;
    const int qtile = (w < 4) ? qa : (31 - qa);
    const int qb_w  = qtile * BQ + (w & 3) * 16;
    const int nkt   = 64 - 2 * qa;

    __shared__ __align__(16) u16 Kt[2][BK * 128];
    __shared__ __align__(16) u16 Et[2][BK * 128];
    __shared__ __align__(16) u16 Vt[2][32 * 128];

    bf16x8 qa_h[4], qa_l[4];
    {
        const int qrow = qb_w + c;
#pragma unroll
        for (int ch = 0; ch < 4; ++ch) {
            const void* src = (ch < 2) ? Qv : PQv;
            const int d0 = (ch & 1) * 32 + 8 * g;
            const size_t off = base + (size_t)qrow * D_DIM + d0;
            float x[8];
            if (IS_F32) {
                const uint4* gp = (const uint4*)((const float*)src + off);
                unpack8<true>(gp[0], gp[1], x);
            } else {
                uint4 a = *(const uint4*)((const u16*)src + off);
                unpack8<false>(a, a, x);
            }
#pragma unroll
            for (int j = 0; j < 8; ++j) x[j] *= 0.1803368801f;
            uint4 hp, lp; split_pack(x, hp, lp);
            u32 hw[4] = {hp.x, hp.y, hp.z, hp.w}, lw[4] = {lp.x, lp.y, lp.z, lp.w};
#pragma unroll
            for (int j = 0; j < 4; ++j) {
                qa_h[ch][2*j]   = (short)(hw[j] & 0xffffu);
                qa_h[ch][2*j+1] = (short)(hw[j] >> 16);
                qa_l[ch][2*j]   = (short)(lw[j] & 0xffffu);
                qa_l[ch][2*j+1] = (short)(lw[j] >> 16);
            }
        }
    }

    float mr = -INFINITY, lr = 0.f;
    f32x4 acc[4];
#pragma unroll
    for (int df = 0; df < 4; ++df) acc[df] = (f32x4){0.f, 0.f, 0.f, 0.f};

    const bool is_ke = (t < 256);
    const int ts = t & 255;
    const int r_t = ts >> 3, j8_t = ts & 7, d_t = ts & 63, kg_t = (ts >> 6) & 3;
    const int ke_wo = r_t * 128 + (j8_t ^ (r_t & 7)) * 8;
    const int v_rr = d_t >> 1;
    const int v_wo = v_rr * 128 + ((4 * (d_t & 1) + kg_t) ^ (v_rr & 7)) * 8;

    StKE Rke; StV Rv;
    auto stage_store = [&](int b) {
        if (is_ke) {
            float x[8]; uint4 hp, lp;
            unpack8<IS_F32>(Rke.k0, Rke.k1, x);
            split_pack(x, hp, lp);
            *(uint4*)(&Kt[b][0] + ke_wo) = hp;
            *(uint4*)(&Kt[b][0] + ke_wo + 64) = lp;
            unpack8<IS_F32>(Rke.e0, Rke.e1, x);
            split_pack(x, hp, lp);
            *(uint4*)(&Et[b][0] + ke_wo) = hp;
            *(uint4*)(&Et[b][0] + ke_wo + 64) = lp;
        } else {
            float x[8]; uint4 hp, lp;
#pragma unroll
            for (int j = 0; j < 8; ++j) {
                if (IS_F32) __builtin_memcpy(&x[j], &Rv.v[j], 4);
                else        x[j] = bf2f(Rv.v[j]);
            }
            split_pack(x, hp, lp);
            *(uint4*)(&Vt[b][0] + v_wo) = hp;
            *(uint4*)(&Vt[b][0] + v_wo + 64) = lp;
        }
    };
    auto issue = [&](int kb) {
        if (is_ke) issue_ke<IS_F32>(Kv, PKv, base, kb, r_t, j8_t, Rke);
        else       issue_v <IS_F32>(Vv, base, kb, d_t, kg_t, Rv);
    };

    issue(0); stage_store(0); issue(BK);
    __syncthreads();

    const int c7 = c & 7;
    const int srcA = 32 * (g & 1) + c, srcB = srcA + 16;
    const int sv = ((4 * (c & 1) + g) ^ ((c >> 1) & 7)) * 8;

    for (int kt = 0; kt < nkt; ++kt) {
        const int cur = kt & 1;
        const int kbase = kt * BK;
        const bool active = (kbase <= qb_w + 15);
        const bool do1 = (kbase + 16 <= qb_w + 15);
        f32x4 s0 = {0,0,0,0}, s1 = {0,0,0,0};
        if (active) {
            const u16* Ktc = &Kt[cur][0];
            const u16* Etc = &Et[cur][0];
            __builtin_amdgcn_s_setprio(1);
#pragma unroll
            for (int ch = 0; ch < 4; ++ch) {
                const u16* Bp = (ch < 2) ? Ktc : Etc;
                const int sh = ((((ch & 1) * 4 + g) ^ c7)) * 8;
                const u16* r0 = Bp + c * 128;
                bf16x8 b0h = *(const bf16x8*)(r0 + sh);
                bf16x8 b0l = *(const bf16x8*)(r0 + sh + 64);
                s0 = MFMA(b0h, qa_h[ch], s0);
                s0 = MFMA(b0l, qa_h[ch], s0);
                s0 = MFMA(b0h, qa_l[ch], s0);
                if (do1) {
                    const u16* r1 = Bp + (c + 16) * 128;
                    bf16x8 b1h = *(const bf16x8*)(r1 + sh);
                    bf16x8 b1l = *(const bf16x8*)(r1 + sh + 64);
                    s1 = MFMA(b1h, qa_h[ch], s1);
                    s1 = MFMA(b1l, qa_h[ch], s1);
                    s1 = MFMA(b1h, qa_l[ch], s1);
                }
            }
            __builtin_amdgcn_s_setprio(0);
        }
        if (kt + 1 < nkt) {
            stage_store(cur ^ 1);
            if (kt + 2 < nkt) issue((kt + 2) * BK);
        }
        if (active) {
            const u16* Vtc = &Vt[cur][0];
            const int qrow = qb_w + c;
#pragma unroll
            for (int i = 0; i < 4; ++i) {
                if (kbase + 4 * g + i > qrow)              s0[i] = -INFINITY;
                if (!do1 || kbase + 16 + 4 * g + i > qrow) s1[i] = -INFINITY;
            }
            float vm = fmaxf(fmaxf(fmaxf(s0[0], s0[1]), fmaxf(s0[2], s0[3])),
                             fmaxf(fmaxf(s1[0], s1[1]), fmaxf(s1[2], s1[3])));
            vm = fmaxf(vm, __shfl_xor(vm, 16));
            vm = fmaxf(vm, __shfl_xor(vm, 32));
            float p0f[4], p1f[4];
#pragma unroll
            for (int i = 0; i < 4; ++i) {
                p0f[i] = exp2f(s0[i] - mr);
                p1f[i] = exp2f(s1[i] - mr);
            }
            if (!__all(vm <= mr + 8.f)) {
                const float mn = fmaxf(mr, vm);
                const float al = exp2f(mr - mn);
                mr = mn;
                lr *= al;
                float al4[4];
#pragma unroll
                for (int i = 0; i < 4; ++i) al4[i] = __shfl(al, 20 * g + i);
#pragma unroll
                for (int df = 0; df < 4; ++df) {
#pragma unroll
                    for (int i = 0; i < 4; ++i) acc[df][i] *= al4[i];
                }
#pragma unroll
                for (int i = 0; i < 4; ++i) {
                    p0f[i] = exp2f(s0[i] - mr);
                    p1f[i] = exp2f(s1[i] - mr);
                }
            }
            float rs = (p0f[0] + p0f[1]) + (p0f[2] + p0f[3])
                     + (p1f[0] + p1f[1]) + (p1f[2] + p1f[3]);
            rs += __shfl_xor(rs, 16);
            rs += __shfl_xor(rs, 32);
            lr += rs;
            u32 w0[4], w1[4];
#pragma unroll
            for (int i = 0; i < 4; ++i) {
                const float x0 = p0f[i];
                u32 b0; __builtin_memcpy(&b0, &x0, 4);
                u32 h0 = b0 & 0xffff0000u; float h0f; __builtin_memcpy(&h0f, &h0, 4);
                float l0f = x0 - h0f; u32 l0; __builtin_memcpy(&l0, &l0f, 4);
                w0[i] = pack_hi16(b0, l0);
                const float x1 = p1f[i];
                u32 b1; __builtin_memcpy(&b1, &x1, 4);
                u32 h1 = b1 & 0xffff0000u; float h1f; __builtin_memcpy(&h1f, &h1, 4);
                float l1f = x1 - h1f; u32 l1; __builtin_memcpy(&l1, &l1f, 4);
                w1[i] = pack_hi16(b1, l1);
            }
            const bool lowhalf = (lane < 32);
            bf16x8 pa_h, pa_l;
#pragma unroll
            for (int i = 0; i < 4; ++i) {
                u32 t0a = (u32)__shfl((int)w0[i], srcA);
                u32 t1a = (u32)__shfl((int)w1[i], srcA);
                u32 t0b = (u32)__shfl((int)w0[i], srcB);
                u32 t1b = (u32)__shfl((int)w1[i], srcB);
                u32 ha = lowhalf ? t0a : t1a;
                u32 hb = lowhalf ? t0b : t1b;
                pa_h[i]     = (short)(ha & 0xffffu);
                pa_h[4 + i] = (short)(hb & 0xffffu);
                pa_l[i]     = (short)(ha >> 16);
                pa_l[4 + i] = (short)(hb >> 16);
            }
            __builtin_amdgcn_s_setprio(1);
#pragma unroll
            for (int df = 0; df < 4; ++df) {
                const u16* vw = Vtc + (8 * df + (c >> 1)) * 128;
                bf16x8 vbh = *(const bf16x8*)(vw + sv);
                bf16x8 vbl = *(const bf16x8*)(vw + sv + 64);
                acc[df] = MFMA(pa_h, vbh, acc[df]);
                acc[df] = MFMA(pa_h, vbl, acc[df]);
                acc[df] = MFMA(pa_l, vbh, acc[df]);
            }
            __builtin_amdgcn_s_setprio(0);
        }
        __syncthreads();
    }

    float inv[4];
#pragma unroll
    for (int i = 0; i < 4; ++i) inv[i] = 1.f / __shfl(lr, 20 * g + i);
    if (IS_F32) {
        float* o = (float*)Ov + base;
#pragma unroll
        for (int df = 0; df < 4; ++df)
#pragma unroll
            for (int i = 0; i < 4; ++i)
                o[(size_t)(qb_w + 4 * g + i) * D_DIM + 16 * df + c] = acc[df][i] * inv[i];
    } else {
        __hip_bfloat16* o = (__hip_bfloat16*)Ov + base;
#pragma unroll
        for (int df = 0; df < 4; ++df)
#pragma unroll
            for (int i = 0; i < 4; ++i)
                o[(size_t)(qb_w + 4 * g + i) * D_DIM + 16 * df + c] =
                    __float2bfloat16(acc[df][i] * inv[i]);
    }
}

extern "C" void kernel_launch(void* const* d_in, const int* in_sizes, int n_in,
                              void* d_out, int out_size, void* d_ws, size_t ws_size,
                              hipStream_t stream) {
    const void* q  = d_in[0];
    const void* k  = d_in[1];
    const void* v  = d_in[2];
    const void* pq = d_in[3];
    const void* pk = d_in[4];
    // d_in[5] = causal mask, recomputed analytically in-kernel.
    int* flag = (int*)d_ws;

    detect_dtype_kernel<<<1, 64, 0, stream>>>((const u16*)q, flag);

    const size_t O_BYTES  = (size_t)2 * 32 * L_SEQ * D_DIM * 4;  // 33.55 MB
    const size_t ML_BYTES = (size_t)2 * 32 * L_SEQ * 2 * 4;      //  1.05 MB
    const size_t WS_NEEDED = 256 + O_BYTES + ML_BYTES;

    if (ws_size >= WS_NEEDED) {
        float* O_ws  = (float*)((char*)d_ws + 256);
        float* ml_ws = (float*)((char*)d_ws + 256 + O_BYTES);
        dim3 ag(16, 32);                     // (q*2+h) x heads = 512 uniform blocks
        attn_split<false><<<ag, 512, 0, stream>>>(q, k, v, pq, pk, O_ws, ml_ws, flag);
        attn_split<true ><<<ag, 512, 0, stream>>>(q, k, v, pq, pk, O_ws, ml_ws, flag);
        dim3 mg(L_SEQ, 32);
        merge_kernel<false><<<mg, 64, 0, stream>>>(O_ws, ml_ws, d_out, flag);
        merge_kernel<true ><<<mg, 64, 0, stream>>>(O_ws, ml_ws, d_out, flag);
    } else {
        dim3 grid(NQT / 2, 32);
        attn_fb<false><<<grid, 512, 0, stream>>>(q, k, v, pq, pk, d_out, flag);
        attn_fb<true ><<<grid, 512, 0, stream>>>(q, k, v, pq, pk, d_out, flag);
    }
}

// Round 13
// 250.259 us; speedup vs baseline: 1.1016x; 1.0759x over previous
//
#include <hip/hip_runtime.h>
#include <hip/hip_bf16.h>

// B=2, H=16, L=2048, D=64. BH=32 flattened heads.
// MFMA flash attention, round 13: FUSED split-K — one 1024-thread block per
// (q-pair, head) holds BOTH k-halves; LDS merge replaces the merge kernel.
//  - Waves 0-7 (group A): keys [0, half*32) of super-tile s; waves 8-15
//    (group B): keys [half*32, 2*half*32). Same 128 q-rows, own K/E/V dbuf.
//  - Segments s = qp then 15-qp -> every block runs exactly 34 trips.
//  - Grid 256 blocks x 1024 thr, LDS 132KB -> exactly 1 block/CU: the
//    block->CU mapping question (r10 null, r11 regression) is closed.
//  - After each seg: B writes (m,l,acc) to LDS scratch (transposed [j][lane],
//    conflict-free), barrier, A combines (same math as r12's proven
//    merge_kernel) and writes final output. No workspace, no merge launches,
//    no 34MB partial round-trip (r12's controllable overhead, ~33us).
// Inner trip code byte-identical to r9/r10/r12: perm-packing, scores->stage->
// softmax/PV order, speculative exp, exp2 softmax, defer-max(+clamp), setprio,
// swapped QK^T, in-register P, role split, swizzled LDS, split-precision
// 3-MFMA. mask input (d_in[5]) = pure causal -> analytic.

typedef unsigned short u16;
typedef unsigned int   u32;
typedef __attribute__((ext_vector_type(8))) short bf16x8;  // 8 bf16 (4 VGPR)
typedef __attribute__((ext_vector_type(4))) float f32x4;   // MFMA acc

#define L_SEQ 2048
#define D_DIM 64
#define BQ    64
#define BK    32
#define NQT   (L_SEQ / BQ)

__device__ __forceinline__ float bf2f(u32 lo16) {
    u32 u = lo16 << 16; float f; __builtin_memcpy(&f, &u, 4); return f;
}

__device__ __forceinline__ u32 pack_hi16(u32 lo_src, u32 hi_src) {
    return __builtin_amdgcn_perm(hi_src, lo_src, 0x07060302u);
}

__global__ void detect_dtype_kernel(const u16* __restrict__ q, int* __restrict__ flag) {
    const int lane = threadIdx.x;
    float x = fabsf(bf2f((u32)q[lane]));
    bool big = !(x <= 100.f);
    unsigned long long m = __ballot(big);
    if (lane == 0) *flag = (m != 0ull) ? 1 : 0;  // 1 = fp32, 0 = bf16
}

__device__ __forceinline__ void split_pack(const float* x, uint4& h, uint4& l) {
    u32 xb[8], rb[8];
#pragma unroll
    for (int j = 0; j < 8; ++j) {
        __builtin_memcpy(&xb[j], &x[j], 4);
        u32 hb = xb[j] & 0xffff0000u;
        float hf; __builtin_memcpy(&hf, &hb, 4);
        float r = x[j] - hf;
        __builtin_memcpy(&rb[j], &r, 4);
    }
    h.x = pack_hi16(xb[0], xb[1]);
    h.y = pack_hi16(xb[2], xb[3]);
    h.z = pack_hi16(xb[4], xb[5]);
    h.w = pack_hi16(xb[6], xb[7]);
    l.x = pack_hi16(rb[0], rb[1]);
    l.y = pack_hi16(rb[2], rb[3]);
    l.z = pack_hi16(rb[4], rb[5]);
    l.w = pack_hi16(rb[6], rb[7]);
}

template<bool IS_F32>
__device__ __forceinline__ void unpack8(const uint4& a, const uint4& b, float* x) {
    if (IS_F32) {
        u32 w[8] = {a.x, a.y, a.z, a.w, b.x, b.y, b.z, b.w};
#pragma unroll
        for (int j = 0; j < 8; ++j) __builtin_memcpy(&x[j], &w[j], 4);
    } else {
        u32 w[4] = {a.x, a.y, a.z, a.w};
#pragma unroll
        for (int j = 0; j < 4; ++j) {
            x[2*j]   = bf2f(w[j] & 0xffffu);
            x[2*j+1] = bf2f(w[j] >> 16);
        }
    }
}

struct StKE { uint4 k0, k1, e0, e1; };
struct StV  { u32 v[8]; };

template<bool IS_F32>
__device__ __forceinline__ void issue_ke(const void* Kv, const void* Ev,
        size_t base, int kbase, int r, int j8, StKE& R) {
    const size_t off = base + (size_t)(kbase + r) * D_DIM + j8 * 8;
    if (IS_F32) {
        const uint4* kp = (const uint4*)((const float*)Kv + off);
        R.k0 = kp[0]; R.k1 = kp[1];
        const uint4* ep = (const uint4*)((const float*)Ev + off);
        R.e0 = ep[0]; R.e1 = ep[1];
    } else {
        R.k0 = *(const uint4*)((const u16*)Kv + off);
        R.e0 = *(const uint4*)((const u16*)Ev + off);
    }
}

template<bool IS_F32>
__device__ __forceinline__ void issue_v(const void* Vv,
        size_t base, int kbase, int d, int kg, StV& R) {
    const size_t off = base + (size_t)(kbase + kg * 8) * D_DIM + d;
    if (IS_F32) {
        const u32* vp = (const u32*)((const float*)Vv + off);
#pragma unroll
        for (int j = 0; j < 8; ++j) R.v[j] = vp[j * D_DIM];
    } else {
        const u16* vp = (const u16*)Vv + off;
#pragma unroll
        for (int j = 0; j < 8; ++j) R.v[j] = (u32)vp[j * D_DIM];
    }
}

#define MFMA(a, b, c) __builtin_amdgcn_mfma_f32_16x16x32_bf16((a), (b), (c), 0, 0, 0)

template<bool IS_F32>
__global__ __launch_bounds__(1024, 4) void attn_fused(
    const void* __restrict__ Qv, const void* __restrict__ Kv,
    const void* __restrict__ Vv, const void* __restrict__ PQv,
    const void* __restrict__ PKv, void* __restrict__ Ov,
    const int* __restrict__ flag)
{
    if (((*flag) != 0) != IS_F32) return;

    const int bh  = blockIdx.y;              // 0..31
    const int qp  = blockIdx.x;              // 0..7 (super-pair)
    const int t   = threadIdx.x;             // 0..1023
    const int grp = t >> 9;                  // 0: keys-half-0, 1: keys-half-1
    const int tg  = t & 511;                 // index within group
    const int w   = tg >> 6;                 // wave in group 0..7
    const int lane = t & 63;
    const int g = lane >> 4, c = lane & 15;
    const size_t base = (size_t)bh * L_SEQ * D_DIM;

    // Per-group double-buffered swizzled tile images + merge scratch.
    __shared__ __align__(16) u16 Kt[2][2][BK * 128];   // [grp][buf] 32 KB
    __shared__ __align__(16) u16 Et[2][2][BK * 128];   // 32 KB
    __shared__ __align__(16) u16 Vt[2][2][32 * 128];   // 32 KB
    __shared__ float Macc[8][16][64];                  // 32 KB (B's acc, [j][lane])
    __shared__ float Mml[8][2][64];                    //  4 KB (B's m,l)
    // total 132 KB -> exactly 1 block/CU

    // staging roles within group: waves 0-3 K+PE, waves 4-7 V
    const bool is_ke = (tg < 256);
    const int ts   = tg & 255;
    const int r_t  = ts >> 3;
    const int j8_t = ts & 7;
    const int d_t  = ts & 63;
    const int kg_t = (ts >> 6) & 3;
    const int ke_wo = r_t * 128 + (j8_t ^ (r_t & 7)) * 8;
    const int v_rr  = d_t >> 1;
    const int v_wo  = v_rr * 128 + ((4 * (d_t & 1) + kg_t) ^ (v_rr & 7)) * 8;

    StKE Rke; StV Rv;

    auto stage_store = [&](int b) {
        if (is_ke) {
            float x[8]; uint4 hp, lp;
            unpack8<IS_F32>(Rke.k0, Rke.k1, x);
            split_pack(x, hp, lp);
            *(uint4*)(&Kt[grp][b][0] + ke_wo)      = hp;
            *(uint4*)(&Kt[grp][b][0] + ke_wo + 64) = lp;
            unpack8<IS_F32>(Rke.e0, Rke.e1, x);
            split_pack(x, hp, lp);
            *(uint4*)(&Et[grp][b][0] + ke_wo)      = hp;
            *(uint4*)(&Et[grp][b][0] + ke_wo + 64) = lp;
        } else {
            float x[8]; uint4 hp, lp;
#pragma unroll
            for (int j = 0; j < 8; ++j) {
                if (IS_F32) __builtin_memcpy(&x[j], &Rv.v[j], 4);
                else        x[j] = bf2f(Rv.v[j]);
            }
            split_pack(x, hp, lp);
            *(uint4*)(&Vt[grp][b][0] + v_wo)      = hp;
            *(uint4*)(&Vt[grp][b][0] + v_wo + 64) = lp;
        }
    };
    auto issue = [&](int kb) {
        if (is_ke) issue_ke<IS_F32>(Kv, PKv, base, kb, r_t, j8_t, Rke);
        else       issue_v <IS_F32>(Vv, base, kb, d_t, kg_t, Rv);
    };

    const int c7 = c & 7;
    const int srcA = 32 * (g & 1) + c;
    const int srcB = srcA + 16;
    const int sv = ((4 * (c & 1) + g) ^ ((c >> 1) & 7)) * 8;

    for (int seg = 0; seg < 2; ++seg) {
        const int s    = seg ? (15 - qp) : qp;   // super-tile 0..15
        const int half = 2 * s + 2;              // k-tiles per half (>=2)
        const int k0   = grp ? half : 0;
        const int klim = k0 + half;
        const int qtile = 2 * s + ((w >= 4) ? 1 : 0);
        const int qb_w  = qtile * BQ + (w & 3) * 16;

        // ---- Q & PE_Q fragments, pre-scaled by 0.125*log2(e) ----
        bf16x8 qa_h[4], qa_l[4];
        {
            const int qrow = qb_w + c;
#pragma unroll
            for (int ch = 0; ch < 4; ++ch) {
                const void* src = (ch < 2) ? Qv : PQv;
                const int d0 = (ch & 1) * 32 + 8 * g;
                const size_t off = base + (size_t)qrow * D_DIM + d0;
                float x[8];
                if (IS_F32) {
                    const uint4* gp = (const uint4*)((const float*)src + off);
                    unpack8<true>(gp[0], gp[1], x);
                } else {
                    uint4 a = *(const uint4*)((const u16*)src + off);
                    unpack8<false>(a, a, x);
                }
#pragma unroll
                for (int j = 0; j < 8; ++j) x[j] *= 0.1803368801f;
                uint4 hp, lp; split_pack(x, hp, lp);
                u32 hw[4] = {hp.x, hp.y, hp.z, hp.w}, lw[4] = {lp.x, lp.y, lp.z, lp.w};
#pragma unroll
                for (int j = 0; j < 4; ++j) {
                    qa_h[ch][2*j]   = (short)(hw[j] & 0xffffu);
                    qa_h[ch][2*j+1] = (short)(hw[j] >> 16);
                    qa_l[ch][2*j]   = (short)(lw[j] & 0xffffu);
                    qa_l[ch][2*j+1] = (short)(lw[j] >> 16);
                }
            }
        }

        float mr = -INFINITY, lr = 0.f;
        f32x4 acc[4];
#pragma unroll
        for (int df = 0; df < 4; ++df) acc[df] = (f32x4){0.f, 0.f, 0.f, 0.f};

        // prologue
        issue(k0 * BK);
        stage_store(0);
        issue((k0 + 1) * BK);
        __syncthreads();

        for (int kt = k0; kt < klim; ++kt) {
            const int cur = (kt - k0) & 1;
            const int kbase = kt * BK;
            const bool active = (kbase <= qb_w + 15);
            const bool do1 = (kbase + 16 <= qb_w + 15);

            // ---- (1) scores: S^T = K.Q^T (+ PEk.PEq^T), split precision ----
            f32x4 s0 = {0,0,0,0}, s1 = {0,0,0,0};
            if (active) {
                const u16* Ktc = &Kt[grp][cur][0];
                const u16* Etc = &Et[grp][cur][0];
                __builtin_amdgcn_s_setprio(1);
#pragma unroll
                for (int ch = 0; ch < 4; ++ch) {
                    const u16* Bp = (ch < 2) ? Ktc : Etc;
                    const int sh = ((((ch & 1) * 4 + g) ^ c7)) * 8;
                    const u16* r0 = Bp + c * 128;
                    bf16x8 b0h = *(const bf16x8*)(r0 + sh);
                    bf16x8 b0l = *(const bf16x8*)(r0 + sh + 64);
                    s0 = MFMA(b0h, qa_h[ch], s0);
                    s0 = MFMA(b0l, qa_h[ch], s0);
                    s0 = MFMA(b0h, qa_l[ch], s0);
                    if (do1) {
                        const u16* r1 = Bp + (c + 16) * 128;
                        bf16x8 b1h = *(const bf16x8*)(r1 + sh);
                        bf16x8 b1l = *(const bf16x8*)(r1 + sh + 64);
                        s1 = MFMA(b1h, qa_h[ch], s1);
                        s1 = MFMA(b1l, qa_h[ch], s1);
                        s1 = MFMA(b1h, qa_l[ch], s1);
                    }
                }
                __builtin_amdgcn_s_setprio(0);
            }

            // ---- (2) stage next tile ----
            if (kt + 1 < klim) {
                stage_store(cur ^ 1);
                if (kt + 2 < klim) issue((kt + 2) * BK);
            }

            // ---- (3) softmax + P + PV ----
            if (active) {
                const u16* Vtc = &Vt[grp][cur][0];
                const int qrow = qb_w + c;
#pragma unroll
                for (int i = 0; i < 4; ++i) {
                    if (kbase + 4 * g + i > qrow)                s0[i] = -INFINITY;
                    if (!do1 || kbase + 16 + 4 * g + i > qrow)   s1[i] = -INFINITY;
                }
                float vm = fmaxf(fmaxf(fmaxf(s0[0], s0[1]), fmaxf(s0[2], s0[3])),
                                 fmaxf(fmaxf(s1[0], s1[1]), fmaxf(s1[2], s1[3])));
                vm = fmaxf(vm, __shfl_xor(vm, 16));
                vm = fmaxf(vm, __shfl_xor(vm, 32));
                float p0f[4], p1f[4];
#pragma unroll
                for (int i = 0; i < 4; ++i) {
                    p0f[i] = exp2f(s0[i] - mr);
                    p1f[i] = exp2f(s1[i] - mr);
                }
                if (!__all(vm <= mr + 8.f)) {
                    const float mn = fmaxf(fmaxf(mr, vm), -1.0e30f);
                    const float al = exp2f(mr - mn);
                    mr = mn;
                    lr *= al;
                    float al4[4];
#pragma unroll
                    for (int i = 0; i < 4; ++i) al4[i] = __shfl(al, 20 * g + i);
#pragma unroll
                    for (int df = 0; df < 4; ++df) {
#pragma unroll
                        for (int i = 0; i < 4; ++i) acc[df][i] *= al4[i];
                    }
#pragma unroll
                    for (int i = 0; i < 4; ++i) {
                        p0f[i] = exp2f(s0[i] - mr);
                        p1f[i] = exp2f(s1[i] - mr);
                    }
                }
                float rs = (p0f[0] + p0f[1]) + (p0f[2] + p0f[3])
                         + (p1f[0] + p1f[1]) + (p1f[2] + p1f[3]);
                rs += __shfl_xor(rs, 16);
                rs += __shfl_xor(rs, 32);
                lr += rs;
                u32 w0[4], w1[4];
#pragma unroll
                for (int i = 0; i < 4; ++i) {
                    const float x0 = p0f[i];
                    u32 b0; __builtin_memcpy(&b0, &x0, 4);
                    u32 h0 = b0 & 0xffff0000u; float h0f; __builtin_memcpy(&h0f, &h0, 4);
                    float l0f = x0 - h0f; u32 l0; __builtin_memcpy(&l0, &l0f, 4);
                    w0[i] = pack_hi16(b0, l0);
                    const float x1 = p1f[i];
                    u32 b1; __builtin_memcpy(&b1, &x1, 4);
                    u32 h1 = b1 & 0xffff0000u; float h1f; __builtin_memcpy(&h1f, &h1, 4);
                    float l1f = x1 - h1f; u32 l1; __builtin_memcpy(&l1, &l1f, 4);
                    w1[i] = pack_hi16(b1, l1);
                }
                const bool lowhalf = (lane < 32);
                bf16x8 pa_h, pa_l;
#pragma unroll
                for (int i = 0; i < 4; ++i) {
                    u32 t0a = (u32)__shfl((int)w0[i], srcA);
                    u32 t1a = (u32)__shfl((int)w1[i], srcA);
                    u32 t0b = (u32)__shfl((int)w0[i], srcB);
                    u32 t1b = (u32)__shfl((int)w1[i], srcB);
                    u32 ha = lowhalf ? t0a : t1a;
                    u32 hb = lowhalf ? t0b : t1b;
                    pa_h[i]     = (short)(ha & 0xffffu);
                    pa_h[4 + i] = (short)(hb & 0xffffu);
                    pa_l[i]     = (short)(ha >> 16);
                    pa_l[4 + i] = (short)(hb >> 16);
                }
                __builtin_amdgcn_s_setprio(1);
#pragma unroll
                for (int df = 0; df < 4; ++df) {
                    const u16* vw = Vtc + (8 * df + (c >> 1)) * 128;
                    bf16x8 vbh = *(const bf16x8*)(vw + sv);
                    bf16x8 vbl = *(const bf16x8*)(vw + sv + 64);
                    acc[df] = MFMA(pa_h, vbh, acc[df]);
                    acc[df] = MFMA(pa_h, vbl, acc[df]);
                    acc[df] = MFMA(pa_l, vbh, acc[df]);
                }
                __builtin_amdgcn_s_setprio(0);
            }
            __syncthreads();
        }

        // ---- LDS merge: B publishes partials; A combines + writes output ----
        if (grp == 1) {
            Mml[w][0][lane] = mr;
            Mml[w][1][lane] = lr;
#pragma unroll
            for (int df = 0; df < 4; ++df)
#pragma unroll
                for (int i = 0; i < 4; ++i)
                    Macc[w][df * 4 + i][lane] = acc[df][i];
        }
        __syncthreads();
        if (grp == 0) {
            const float m1 = Mml[w][0][lane];
            const float l1 = Mml[w][1][lane];
            const float m  = fmaxf(mr, m1);      // mr finite (key 0 in half 0)
            const float wa = exp2f(mr - m);
            const float wb = exp2f(m1 - m);      // m1=-inf -> 0
            const float invl = 1.f / (lr * wa + l1 * wb);
            float war[4], wbr[4], ir[4];
#pragma unroll
            for (int i = 0; i < 4; ++i) {
                war[i] = __shfl(wa,   20 * g + i);
                wbr[i] = __shfl(wb,   20 * g + i);
                ir[i]  = __shfl(invl, 20 * g + i);
            }
            if (IS_F32) {
                float* o = (float*)Ov + base;
#pragma unroll
                for (int df = 0; df < 4; ++df)
#pragma unroll
                    for (int i = 0; i < 4; ++i) {
                        const float ob = Macc[w][df * 4 + i][lane];
                        o[(size_t)(qb_w + 4 * g + i) * D_DIM + 16 * df + c] =
                            (acc[df][i] * war[i] + ob * wbr[i]) * ir[i];
                    }
            } else {
                __hip_bfloat16* o = (__hip_bfloat16*)Ov + base;
#pragma unroll
                for (int df = 0; df < 4; ++df)
#pragma unroll
                    for (int i = 0; i < 4; ++i) {
                        const float ob = Macc[w][df * 4 + i][lane];
                        o[(size_t)(qb_w + 4 * g + i) * D_DIM + 16 * df + c] =
                            __float2bfloat16((acc[df][i] * war[i] + ob * wbr[i]) * ir[i]);
                    }
            }
        }
        // No extra barrier needed: B's next Macc/Mml write is after seg1's
        // prologue barrier + >=2 trip barriers, long after A's reads.
    }
}

extern "C" void kernel_launch(void* const* d_in, const int* in_sizes, int n_in,
                              void* d_out, int out_size, void* d_ws, size_t ws_size,
                              hipStream_t stream) {
    const void* q  = d_in[0];
    const void* k  = d_in[1];
    const void* v  = d_in[2];
    const void* pq = d_in[3];
    const void* pk = d_in[4];
    // d_in[5] = causal mask, recomputed analytically in-kernel.
    int* flag = (int*)d_ws;

    detect_dtype_kernel<<<1, 64, 0, stream>>>((const u16*)q, flag);

    dim3 grid(8, 32);                        // 256 blocks = exactly 1 per CU
    attn_fused<false><<<grid, 1024, 0, stream>>>(q, k, v, pq, pk, d_out, flag);
    attn_fused<true ><<<grid, 1024, 0, stream>>>(q, k, v, pq, pk, d_out, flag);
}